// Round 1
// baseline (987.638 us; speedup 1.0000x reference)
//
#include <hip/hip_runtime.h>

// Problem constants (fixed by the reference problem)
#define B_SZ   4
#define NTOK   5440          // sum of level H*W: 4096+1024+256+64
#define MTOT   (B_SZ*NTOK)   // 21760 token rows
#define DMODEL 256
#define FFDIM  1024
#define NH     8
#define DH     32
#define NL     4
#define NP     4

// ---------------------------------------------------------------------------
// Generic tiled fp32 GEMM:  C[M,Nout] = (A (+A2)) @ W[Nout,K]^T + bias
// optional relu, optional per-row zero mask (padding_mask semantics).
// Tiles: BM=64, BN=64, BK=16; 256 threads; 4x4 outputs per thread.
// Requires M%64==0, Nout%64==0, K%16==0 (all true here).
// ---------------------------------------------------------------------------
__global__ __launch_bounds__(256)
void gemm_bias_kernel(const float* __restrict__ A, const float* __restrict__ A2,
                      const float* __restrict__ W, const float* __restrict__ bias,
                      const unsigned char* __restrict__ rowmask,
                      float* __restrict__ C, int M, int Nout, int K, int relu)
{
    __shared__ float As[16][64];
    __shared__ float Ws[16][64];
    const int tid = threadIdx.x;
    const int tx = tid & 15, ty = tid >> 4;
    const int row0 = blockIdx.x * 64;
    const int col0 = blockIdx.y * 64;
    const int lr = tid >> 2;          // 0..63  (tile row to load)
    const int lk = (tid & 3) << 2;    // 0,4,8,12 (k offset, float4)
    const float* Aptr  = A + (size_t)(row0 + lr) * K + lk;
    const float* Wptr  = W + (size_t)(col0 + lr) * K + lk;
    const float* A2ptr = A2 ? (A2 + (size_t)(row0 + lr) * K + lk) : nullptr;

    float acc[4][4] = {{0.f,0.f,0.f,0.f},{0.f,0.f,0.f,0.f},
                       {0.f,0.f,0.f,0.f},{0.f,0.f,0.f,0.f}};

    for (int k0 = 0; k0 < K; k0 += 16) {
        float4 av = *(const float4*)(Aptr + k0);
        if (A2ptr) {
            float4 a2 = *(const float4*)(A2ptr + k0);
            av.x += a2.x; av.y += a2.y; av.z += a2.z; av.w += a2.w;
        }
        float4 wv = *(const float4*)(Wptr + k0);
        __syncthreads();   // previous iter's compute done before overwriting LDS
        As[lk+0][lr] = av.x; As[lk+1][lr] = av.y; As[lk+2][lr] = av.z; As[lk+3][lr] = av.w;
        Ws[lk+0][lr] = wv.x; Ws[lk+1][lr] = wv.y; Ws[lk+2][lr] = wv.z; Ws[lk+3][lr] = wv.w;
        __syncthreads();
        #pragma unroll
        for (int kk = 0; kk < 16; ++kk) {
            const float4 a = *(const float4*)&As[kk][ty << 2];
            const float4 b = *(const float4*)&Ws[kk][tx << 2];
            const float ar[4] = {a.x, a.y, a.z, a.w};
            const float br[4] = {b.x, b.y, b.z, b.w};
            #pragma unroll
            for (int i = 0; i < 4; ++i)
                #pragma unroll
                for (int j = 0; j < 4; ++j)
                    acc[i][j] += ar[i] * br[j];
        }
    }

    const int col = col0 + (tx << 2);
    const float4 bv = *(const float4*)(bias + col);
    #pragma unroll
    for (int i = 0; i < 4; ++i) {
        const int row = row0 + (ty << 2) + i;
        float4 o;
        o.x = acc[i][0] + bv.x; o.y = acc[i][1] + bv.y;
        o.z = acc[i][2] + bv.z; o.w = acc[i][3] + bv.w;
        if (relu) { o.x = fmaxf(o.x, 0.f); o.y = fmaxf(o.y, 0.f);
                    o.z = fmaxf(o.z, 0.f); o.w = fmaxf(o.w, 0.f); }
        if (rowmask && rowmask[row]) { o.x = 0.f; o.y = 0.f; o.z = 0.f; o.w = 0.f; }
        *(float4*)(C + (size_t)row * Nout + col) = o;
    }
}

// ---------------------------------------------------------------------------
// Deformable sampling. One 256-thread block per token.
// thread = h*32 + d  (head, head-channel). Offsets/logits/refpoints staged in
// LDS; softmax over the 16 (level,point) logits per head done in-register.
// value layout: [(b*NTOK + spatial_idx)*256 + h*32 + d]
// ---------------------------------------------------------------------------
__global__ __launch_bounds__(256)
void sampling_kernel(const float* __restrict__ value, const float* __restrict__ offb,
                     const float* __restrict__ attnb, const float* __restrict__ refp,
                     float* __restrict__ samp)
{
    __shared__ float s_off[256];   // (NH, NL, NP, 2)
    __shared__ float s_log[128];   // (NH, NL*NP)
    __shared__ float s_ref[8];     // (NL, 2)
    const int t   = blockIdx.x;            // global token (b*NTOK + n)
    const int b   = t / NTOK;
    const int tid = threadIdx.x;

    s_off[tid] = offb[(size_t)t * 256 + tid];
    if (tid < 128) s_log[tid] = attnb[(size_t)t * 128 + tid];
    if (tid < 8)   s_ref[tid] = refp[(size_t)t * 8 + tid];
    __syncthreads();

    const int h = tid >> 5, d = tid & 31;

    // softmax (redundant across the 32 lanes of a head; cheap)
    float mx = -1e30f;
    #pragma unroll
    for (int i = 0; i < 16; ++i) mx = fmaxf(mx, s_log[h * 16 + i]);
    float ssum = 0.f;
    #pragma unroll
    for (int i = 0; i < 16; ++i) ssum += __expf(s_log[h * 16 + i] - mx);
    const float inv = 1.f / ssum;

    const int HWs[4] = {64, 32, 16, 8};
    const int LST[4] = {0, 4096, 5120, 5376};

    float acc = 0.f;
    const float* vb = value + (size_t)b * NTOK * 256 + h * 32 + d;

    #pragma unroll
    for (int l = 0; l < 4; ++l) {
        const int   Wl = HWs[l], Hl = HWs[l];
        const float fW = (float)Wl, fH = (float)Hl;
        const float rx = s_ref[l * 2 + 0], ry = s_ref[l * 2 + 1];
        const float* vl = vb + (size_t)LST[l] * 256;
        #pragma unroll
        for (int p = 0; p < 4; ++p) {
            const float ox = s_off[h * 32 + l * 8 + p * 2 + 0];
            const float oy = s_off[h * 32 + l * 8 + p * 2 + 1];
            // loc*W - 0.5 == ref*W + off - 0.5  (normalizer [W,H] cancels)
            const float x = rx * fW + ox - 0.5f;
            const float y = ry * fH + oy - 0.5f;
            const float aw = __expf(s_log[h * 16 + l * 4 + p] - mx) * inv;
            const float x0 = floorf(x), y0 = floorf(y);
            const float fx = x - x0, fy = y - y0;
            const int ix = (int)x0, iy = (int)y0;
            float sv = 0.f;
            #pragma unroll
            for (int dy = 0; dy < 2; ++dy) {
                #pragma unroll
                for (int dx = 0; dx < 2; ++dx) {
                    const int xi = ix + dx, yi = iy + dy;
                    if (xi >= 0 && xi < Wl && yi >= 0 && yi < Hl) {
                        const float wgt = (dx ? fx : 1.f - fx) * (dy ? fy : 1.f - fy);
                        sv += vl[(size_t)(yi * Wl + xi) * 256] * wgt;
                    }
                }
            }
            acc += sv * aw;
        }
    }
    samp[(size_t)t * 256 + tid] = acc;
}

// ---------------------------------------------------------------------------
// Fused residual + LayerNorm over D=256. One wave per row (4 rows/block).
// out = (v - mean)/sqrt(var+1e-5)*g + be,  v = resid + y
// ---------------------------------------------------------------------------
__global__ __launch_bounds__(256)
void ln_kernel(const float* __restrict__ resid, const float* __restrict__ y,
               const float* __restrict__ g, const float* __restrict__ be,
               float* __restrict__ out)
{
    const int wave = threadIdx.x >> 6;
    const int lane = threadIdx.x & 63;
    const int row  = blockIdx.x * 4 + wave;
    const size_t base = (size_t)row * 256 + (lane << 2);

    const float4 r = *(const float4*)(resid + base);
    float4 v       = *(const float4*)(y + base);
    v.x += r.x; v.y += r.y; v.z += r.z; v.w += r.w;

    float s  = v.x + v.y + v.z + v.w;
    float ss = v.x * v.x + v.y * v.y + v.z * v.z + v.w * v.w;
    #pragma unroll
    for (int off = 32; off; off >>= 1) {
        s  += __shfl_xor(s, off, 64);
        ss += __shfl_xor(ss, off, 64);
    }
    const float mean = s * (1.f / 256.f);
    const float var  = ss * (1.f / 256.f) - mean * mean;
    const float rstd = rsqrtf(var + 1e-5f);

    const float4 gv = *(const float4*)(g  + (lane << 2));
    const float4 bv = *(const float4*)(be + (lane << 2));
    float4 o;
    o.x = (v.x - mean) * rstd * gv.x + bv.x;
    o.y = (v.y - mean) * rstd * gv.y + bv.y;
    o.z = (v.z - mean) * rstd * gv.z + bv.z;
    o.w = (v.w - mean) * rstd * gv.w + bv.w;
    *(float4*)(out + base) = o;
}

// ---------------------------------------------------------------------------
extern "C" void kernel_launch(void* const* d_in, const int* in_sizes, int n_in,
                              void* d_out, int out_size, void* d_ws, size_t ws_size,
                              hipStream_t stream) {
    const float* src     = (const float*)d_in[0];
    const float* pos     = (const float*)d_in[1];
    const float* refp    = (const float*)d_in[2];
    const float* w_value = (const float*)d_in[3];
    const float* b_value = (const float*)d_in[4];
    const float* w_off   = (const float*)d_in[5];
    const float* b_off   = (const float*)d_in[6];
    const float* w_attn  = (const float*)d_in[7];
    const float* b_attn  = (const float*)d_in[8];
    const float* w_out   = (const float*)d_in[9];
    const float* b_out   = (const float*)d_in[10];
    const float* g1      = (const float*)d_in[11];
    const float* be1     = (const float*)d_in[12];
    const float* w1      = (const float*)d_in[13];
    const float* b1      = (const float*)d_in[14];
    const float* w2      = (const float*)d_in[15];
    const float* b2      = (const float*)d_in[16];
    const float* g2      = (const float*)d_in[17];
    const float* be2     = (const float*)d_in[18];
    const unsigned char* pmask = (const unsigned char*)d_in[21]; // all-false in this problem

    // Workspace layout (floats). Reuse: aout <- offb (consumed by sampling),
    // f <- value (consumed by sampling). Peak use ~145 MB.
    float* ws    = (float*)d_ws;
    float* value = ws;                      // MTOT*256
    float* offb  = value + (size_t)MTOT * 256;   // MTOT*256
    float* attnb = offb  + (size_t)MTOT * 256;   // MTOT*128
    float* samp  = attnb + (size_t)MTOT * 128;   // MTOT*256
    float* x     = samp  + (size_t)MTOT * 256;   // MTOT*256
    float* h     = x     + (size_t)MTOT * 256;   // NTOK*1024 (FFN chunk)
    float* aout  = offb;
    float* f     = value;

    const dim3 blk(256);

    // value = src @ w_value^T + b_value  (+ padding mask zero)
    gemm_bias_kernel<<<dim3(MTOT / 64, DMODEL / 64), blk, 0, stream>>>(
        src, nullptr, w_value, b_value, pmask, value, MTOT, DMODEL, DMODEL, 0);
    // off = (src+pos) @ w_off^T + b_off
    gemm_bias_kernel<<<dim3(MTOT / 64, DMODEL / 64), blk, 0, stream>>>(
        src, pos, w_off, b_off, nullptr, offb, MTOT, DMODEL, DMODEL, 0);
    // attn logits = (src+pos) @ w_attn^T + b_attn
    gemm_bias_kernel<<<dim3(MTOT / 64, 128 / 64), blk, 0, stream>>>(
        src, pos, w_attn, b_attn, nullptr, attnb, MTOT, 128, DMODEL, 0);
    // deformable sampling
    sampling_kernel<<<dim3(MTOT), blk, 0, stream>>>(value, offb, attnb, refp, samp);
    // a = samp @ w_out^T + b_out
    gemm_bias_kernel<<<dim3(MTOT / 64, DMODEL / 64), blk, 0, stream>>>(
        samp, nullptr, w_out, b_out, nullptr, aout, MTOT, DMODEL, DMODEL, 0);
    // x = LN(src + a)
    ln_kernel<<<dim3(MTOT / 4), blk, 0, stream>>>(src, aout, g1, be1, x);
    // FFN, chunked over tokens to cap the hidden buffer at NTOK*1024 floats
    for (int c = 0; c < 4; ++c) {
        const float* xc = x + (size_t)c * NTOK * 256;
        float*       fc = f + (size_t)c * NTOK * 256;
        gemm_bias_kernel<<<dim3(NTOK / 64, FFDIM / 64), blk, 0, stream>>>(
            xc, nullptr, w1, b1, nullptr, h, NTOK, FFDIM, DMODEL, 1);
        gemm_bias_kernel<<<dim3(NTOK / 64, DMODEL / 64), blk, 0, stream>>>(
            h, nullptr, w2, b2, nullptr, fc, NTOK, DMODEL, FFDIM, 0);
    }
    // out = LN(x + f)
    ln_kernel<<<dim3(MTOT / 4), blk, 0, stream>>>(x, f, g2, be2, (float*)d_out);
}

// Round 2
// 443.356 us; speedup vs baseline: 2.2276x; 2.2276x over previous
//
#include <hip/hip_runtime.h>

// Problem constants
#define B_SZ   4
#define NTOK   5440
#define MTOT   (B_SZ*NTOK)   // 21760
#define DMODEL 256
#define FFDIM  1024
#define NH     8
#define DH     32

typedef __attribute__((ext_vector_type(8))) __bf16 bf16x8;
typedef __attribute__((ext_vector_type(4))) float  f32x4;

static __device__ __forceinline__ unsigned short f2b(float f) {
    unsigned u = __builtin_bit_cast(unsigned, f);
    u = (u + 0x7FFF + ((u >> 16) & 1)) >> 16;     // RNE, NaN ignored (inputs finite)
    return (unsigned short)u;
}
static __device__ __forceinline__ float b2f(unsigned short s) {
    return __builtin_bit_cast(float, (unsigned)s << 16);
}

// ---------------------------------------------------------------------------
// bf16 MFMA GEMM: C[M,Nout] = A[M,K] @ Wt[Nout,K]^T + bias, opt relu/rowmask.
// 128x128 tile, BK=32, 256 threads (4 waves, 2x2 of 64x64), 16x16x32 MFMA.
// A/Wt bf16 (as ushort). Output fp32 (Cf) or bf16 (Cb). M%128==0, Nout%128==0,
// K%32==0 required (true for all uses here).
// ---------------------------------------------------------------------------
__global__ __launch_bounds__(256)
void mfma_gemm(const unsigned short* __restrict__ A,
               const unsigned short* __restrict__ Wt,
               const float* __restrict__ bias,
               const unsigned char* __restrict__ rowmask,
               float* __restrict__ Cf, unsigned short* __restrict__ Cb,
               int M, int Nout, int K, int relu)
{
    __shared__ unsigned short As[128 * 32];
    __shared__ unsigned short Bs[128 * 32];
    const int tid  = threadIdx.x;
    const int lane = tid & 63;
    const int wave = tid >> 6;
    const int row0 = blockIdx.x * 128, col0 = blockIdx.y * 128;
    const int wr = (wave >> 1) * 64;      // wave row offset in tile
    const int wc = (wave & 1) * 64;       // wave col offset in tile
    const int mrow = lane & 15, quad = lane >> 4;

    f32x4 acc[4][4] = {};

    // staging indices: idx = i*256+tid; row = idx>>2 (4x 16B chunks per row of 32 bf16)
    const int r0i = (0 * 256 + tid) >> 2, k0i = ((0 * 256 + tid) & 3) * 8;
    const int r1i = (1 * 256 + tid) >> 2, k1i = ((1 * 256 + tid) & 3) * 8;
    const int lds0 = (0 * 256 + wave * 64) * 8;   // shorts, wave-uniform base
    const int lds1 = (1 * 256 + wave * 64) * 8;

    for (int k0 = 0; k0 < K; k0 += 32) {
        __syncthreads();   // previous iteration's MFMA reads done
        {
            const unsigned short* ga0 = A  + (size_t)(row0 + r0i) * K + k0 + k0i;
            const unsigned short* gb0 = Wt + (size_t)(col0 + r0i) * K + k0 + k0i;
            const unsigned short* ga1 = A  + (size_t)(row0 + r1i) * K + k0 + k1i;
            const unsigned short* gb1 = Wt + (size_t)(col0 + r1i) * K + k0 + k1i;
            __builtin_amdgcn_global_load_lds((const __attribute__((address_space(1))) void*)ga0,
                                             (__attribute__((address_space(3))) void*)&As[lds0], 16, 0, 0);
            __builtin_amdgcn_global_load_lds((const __attribute__((address_space(1))) void*)gb0,
                                             (__attribute__((address_space(3))) void*)&Bs[lds0], 16, 0, 0);
            __builtin_amdgcn_global_load_lds((const __attribute__((address_space(1))) void*)ga1,
                                             (__attribute__((address_space(3))) void*)&As[lds1], 16, 0, 0);
            __builtin_amdgcn_global_load_lds((const __attribute__((address_space(1))) void*)gb1,
                                             (__attribute__((address_space(3))) void*)&Bs[lds1], 16, 0, 0);
        }
        __syncthreads();   // drains vmcnt before barrier -> tiles visible

        bf16x8 af[4], bfr[4];
        #pragma unroll
        for (int t4 = 0; t4 < 4; ++t4) {
            af[t4]  = *(const bf16x8*)&As[(wr + t4 * 16 + mrow) * 32 + quad * 8];
            bfr[t4] = *(const bf16x8*)&Bs[(wc + t4 * 16 + mrow) * 32 + quad * 8];
        }
        #pragma unroll
        for (int ti = 0; ti < 4; ++ti)
            #pragma unroll
            for (int tj = 0; tj < 4; ++tj)
                acc[ti][tj] = __builtin_amdgcn_mfma_f32_16x16x32_bf16(
                                  af[ti], bfr[tj], acc[ti][tj], 0, 0, 0);
    }

    // epilogue: D layout col=lane&15, row=quad*4+reg  [measured m89/m91]
    #pragma unroll
    for (int tj = 0; tj < 4; ++tj) {
        const int col = col0 + wc + tj * 16 + mrow;
        const float bv = bias ? bias[col] : 0.f;
        #pragma unroll
        for (int ti = 0; ti < 4; ++ti) {
            #pragma unroll
            for (int r = 0; r < 4; ++r) {
                const int row = row0 + wr + ti * 16 + quad * 4 + r;
                float v = acc[ti][tj][r] + bv;
                if (relu) v = fmaxf(v, 0.f);
                if (rowmask && rowmask[row]) v = 0.f;
                if (Cf) Cf[(size_t)row * Nout + col] = v;
                else    Cb[(size_t)row * Nout + col] = f2b(v);
            }
        }
    }
}

// ---------------------------------------------------------------------------
// Deformable sampling, two-phase. One 256-thread block per token.
// Phase A (128 threads = (head,point)): softmax weight + 4 bilinear corner
//   (element-offset, combined-weight) pairs -> LDS.
// Phase B (256 threads = (head,channel)): 64 gather+fma from bf16 value.
// ---------------------------------------------------------------------------
__global__ __launch_bounds__(256)
void sampling_kernel(const unsigned short* __restrict__ value,
                     const unsigned short* __restrict__ offb,
                     const unsigned short* __restrict__ attnb,
                     const float* __restrict__ refp,
                     unsigned short* __restrict__ samp)
{
    __shared__ int   s_idx[512];
    __shared__ float s_w[512];
    const int t   = blockIdx.x;
    const int b   = t / NTOK;
    const int tid = threadIdx.x;

    if (tid < 128) {
        const int h = tid >> 4, i16 = tid & 15, l = i16 >> 2;
        const float logit = b2f(attnb[(size_t)t * 128 + h * 16 + i16]);
        float mx = logit;
        #pragma unroll
        for (int o = 8; o; o >>= 1) mx = fmaxf(mx, __shfl_xor(mx, o, 16));
        const float e = __expf(logit - mx);
        float ssum = e;
        #pragma unroll
        for (int o = 8; o; o >>= 1) ssum += __shfl_xor(ssum, o, 16);
        const float aw = e / ssum;

        const int   Wl_t[4]  = {64, 32, 16, 8};
        const int   LST_t[4] = {0, 4096, 5120, 5376};
        const int   Wl  = Wl_t[l];
        const int   LST = LST_t[l];
        const float fW  = (float)Wl;

        const float ox = b2f(offb[(size_t)t * 256 + h * 32 + i16 * 2 + 0]);
        const float oy = b2f(offb[(size_t)t * 256 + h * 32 + i16 * 2 + 1]);
        const float rx = refp[(size_t)t * 8 + l * 2 + 0];
        const float ry = refp[(size_t)t * 8 + l * 2 + 1];
        const float x  = rx * fW + ox - 0.5f;   // normalizer cancels: H==W per level
        const float y  = ry * fW + oy - 0.5f;
        const float x0 = floorf(x), y0 = floorf(y);
        const float fx = x - x0, fy = y - y0;
        const int   ix = (int)x0, iy = (int)y0;

        #pragma unroll
        for (int dy = 0; dy < 2; ++dy) {
            #pragma unroll
            for (int dx = 0; dx < 2; ++dx) {
                const int xi = ix + dx, yi = iy + dy;
                const bool valid = (xi >= 0) & (xi < Wl) & (yi >= 0) & (yi < Wl);
                const float w = valid ? aw * (dx ? fx : 1.f - fx) * (dy ? fy : 1.f - fy) : 0.f;
                const int idx = valid ? (LST + yi * Wl + xi) * 256 : 0;
                s_w[tid * 4 + dy * 2 + dx]   = w;
                s_idx[tid * 4 + dy * 2 + dx] = idx;
            }
        }
    }
    __syncthreads();

    const int h = tid >> 5, d = tid & 31;
    const unsigned short* vb = value + (size_t)b * NTOK * 256 + h * 32 + d;
    float acc = 0.f;
    #pragma unroll
    for (int p = 0; p < 16; ++p) {
        const int base = (h * 16 + p) * 4;
        #pragma unroll
        for (int c = 0; c < 4; ++c)
            acc += b2f(vb[s_idx[base + c]]) * s_w[base + c];
    }
    samp[(size_t)t * 256 + tid] = f2b(acc);
}

// ---------------------------------------------------------------------------
// Fused residual + LayerNorm (D=256), one wave per row; optional bf16 copy.
// ---------------------------------------------------------------------------
__global__ __launch_bounds__(256)
void ln_kernel(const float* __restrict__ resid, const float* __restrict__ y,
               const float* __restrict__ g, const float* __restrict__ be,
               float* __restrict__ out_f, unsigned short* __restrict__ out_b)
{
    const int wave = threadIdx.x >> 6;
    const int lane = threadIdx.x & 63;
    const int row  = blockIdx.x * 4 + wave;
    const size_t base = (size_t)row * 256 + (lane << 2);

    const float4 r = *(const float4*)(resid + base);
    float4 v       = *(const float4*)(y + base);
    v.x += r.x; v.y += r.y; v.z += r.z; v.w += r.w;

    float s  = v.x + v.y + v.z + v.w;
    float ss = v.x * v.x + v.y * v.y + v.z * v.z + v.w * v.w;
    #pragma unroll
    for (int off = 32; off; off >>= 1) {
        s  += __shfl_xor(s, off, 64);
        ss += __shfl_xor(ss, off, 64);
    }
    const float mean = s * (1.f / 256.f);
    const float var  = ss * (1.f / 256.f) - mean * mean;
    const float rstd = rsqrtf(var + 1e-5f);

    const float4 gv = *(const float4*)(g  + (lane << 2));
    const float4 bv = *(const float4*)(be + (lane << 2));
    float4 o;
    o.x = (v.x - mean) * rstd * gv.x + bv.x;
    o.y = (v.y - mean) * rstd * gv.y + bv.y;
    o.z = (v.z - mean) * rstd * gv.z + bv.z;
    o.w = (v.w - mean) * rstd * gv.w + bv.w;
    *(float4*)(out_f + base) = o;
    if (out_b) {
        ushort4 u; u.x = f2b(o.x); u.y = f2b(o.y); u.z = f2b(o.z); u.w = f2b(o.w);
        *(ushort4*)(out_b + base) = u;
    }
}

// ---------------------------------------------------------------------------
// q_bf = bf16(src+pos), src_bf = bf16(src)   (float4 -> ushort4)
// ---------------------------------------------------------------------------
__global__ __launch_bounds__(256)
void addcvt_kernel(const float* __restrict__ src, const float* __restrict__ pos,
                   unsigned short* __restrict__ q_bf, unsigned short* __restrict__ src_bf)
{
    const size_t v = (size_t)blockIdx.x * 256 + threadIdx.x;  // float4 index
    const float4 s = ((const float4*)src)[v];
    const float4 p = ((const float4*)pos)[v];
    ushort4 qo, so;
    qo.x = f2b(s.x + p.x); qo.y = f2b(s.y + p.y); qo.z = f2b(s.z + p.z); qo.w = f2b(s.w + p.w);
    so.x = f2b(s.x);       so.y = f2b(s.y);       so.z = f2b(s.z);       so.w = f2b(s.w);
    ((ushort4*)q_bf)[v]   = qo;
    ((ushort4*)src_bf)[v] = so;
}

// ---------------------------------------------------------------------------
// Fused fp32->bf16 conversion of all 6 weight matrices (one launch).
// Segment sizes in float4 units: 16384,16384,8192,16384,65536,65536 (sum 188416)
// ---------------------------------------------------------------------------
__global__ __launch_bounds__(256)
void wcvt_kernel(const float* __restrict__ a0, const float* __restrict__ a1,
                 const float* __restrict__ a2, const float* __restrict__ a3,
                 const float* __restrict__ a4, const float* __restrict__ a5,
                 unsigned short* __restrict__ o0, unsigned short* __restrict__ o1,
                 unsigned short* __restrict__ o2, unsigned short* __restrict__ o3,
                 unsigned short* __restrict__ o4, unsigned short* __restrict__ o5)
{
    int v = blockIdx.x * 256 + threadIdx.x;
    const float* s; unsigned short* d; int off;
    if      (v <  16384) { s = a0; d = o0; off = v; }
    else if (v <  32768) { s = a1; d = o1; off = v - 16384; }
    else if (v <  40960) { s = a2; d = o2; off = v - 32768; }
    else if (v <  57344) { s = a3; d = o3; off = v - 40960; }
    else if (v < 122880) { s = a4; d = o4; off = v - 57344; }
    else                 { s = a5; d = o5; off = v - 122880; }
    const float4 f = ((const float4*)s)[off];
    ushort4 u; u.x = f2b(f.x); u.y = f2b(f.y); u.z = f2b(f.z); u.w = f2b(f.w);
    ((ushort4*)d)[off] = u;
}

// ---------------------------------------------------------------------------
extern "C" void kernel_launch(void* const* d_in, const int* in_sizes, int n_in,
                              void* d_out, int out_size, void* d_ws, size_t ws_size,
                              hipStream_t stream) {
    const float* src     = (const float*)d_in[0];
    const float* pos     = (const float*)d_in[1];
    const float* refp    = (const float*)d_in[2];
    const float* w_value = (const float*)d_in[3];
    const float* b_value = (const float*)d_in[4];
    const float* w_off   = (const float*)d_in[5];
    const float* b_off   = (const float*)d_in[6];
    const float* w_attn  = (const float*)d_in[7];
    const float* b_attn  = (const float*)d_in[8];
    const float* w_out   = (const float*)d_in[9];
    const float* b_out   = (const float*)d_in[10];
    const float* g1      = (const float*)d_in[11];
    const float* be1     = (const float*)d_in[12];
    const float* w1      = (const float*)d_in[13];
    const float* b1      = (const float*)d_in[14];
    const float* w2      = (const float*)d_in[15];
    const float* b2      = (const float*)d_in[16];
    const float* g2      = (const float*)d_in[17];
    const float* be2     = (const float*)d_in[18];
    const unsigned char* pmask = (const unsigned char*)d_in[21];

    // ---- workspace layout (bytes); total 118.5 MB ----
    char* ws = (char*)d_ws;
    const size_t SZ_BF  = (size_t)MTOT * 256 * 2;     // 11,141,120
    unsigned short* q_bf    = (unsigned short*)(ws);
    unsigned short* src_bf  = (unsigned short*)(ws + SZ_BF);
    unsigned short* value_b = (unsigned short*)(ws + 2 * SZ_BF);
    unsigned short* offb    = (unsigned short*)(ws + 3 * SZ_BF);
    unsigned short* attnb   = (unsigned short*)(ws + 4 * SZ_BF);               // MTOT*128
    unsigned short* samp    = (unsigned short*)(ws + 4 * SZ_BF + SZ_BF / 2);
    float*          x       = (float*)(ws + 5 * SZ_BF + SZ_BF / 2);            // MTOT*256 f32
    unsigned short* x_bf    = (unsigned short*)(ws + 7 * SZ_BF + SZ_BF / 2);
    unsigned short* h_bf    = (unsigned short*)(ws + 8 * SZ_BF + SZ_BF / 2);   // (MTOT/2)*1024
    unsigned short* wts     = (unsigned short*)(ws + 10 * SZ_BF + SZ_BF / 2);
    // aliases (lifetimes disjoint, single stream):
    float* aout = (float*)(ws);                // over q_bf+src_bf
    float* f    = (float*)(ws + 3 * SZ_BF);    // over offb+attnb+samp(1/2)

    unsigned short* wv_b    = wts;
    unsigned short* woff_b  = wv_b   + 65536;
    unsigned short* wattn_b = woff_b + 65536;
    unsigned short* wout_b  = wattn_b + 32768;
    unsigned short* w1_b    = wout_b + 65536;
    unsigned short* w2_b    = w1_b   + 262144;

    const dim3 blk(256);

    // conversions
    addcvt_kernel<<<dim3(MTOT * 256 / 4 / 256), blk, 0, stream>>>(src, pos, q_bf, src_bf);
    wcvt_kernel<<<dim3(736), blk, 0, stream>>>(w_value, w_off, w_attn, w_out, w1, w2,
                                               wv_b, woff_b, wattn_b, wout_b, w1_b, w2_b);
    // value = src @ w_value^T + b_value (+mask) -> bf16
    mfma_gemm<<<dim3(MTOT / 128, 2), blk, 0, stream>>>(
        src_bf, wv_b, b_value, pmask, nullptr, value_b, MTOT, DMODEL, DMODEL, 0);
    // off = q @ w_off^T + b_off -> bf16
    mfma_gemm<<<dim3(MTOT / 128, 2), blk, 0, stream>>>(
        q_bf, woff_b, b_off, nullptr, nullptr, offb, MTOT, DMODEL, DMODEL, 0);
    // attn logits -> bf16
    mfma_gemm<<<dim3(MTOT / 128, 1), blk, 0, stream>>>(
        q_bf, wattn_b, b_attn, nullptr, nullptr, attnb, MTOT, 128, DMODEL, 0);
    // deformable sampling -> bf16
    sampling_kernel<<<dim3(MTOT), blk, 0, stream>>>(value_b, offb, attnb, refp, samp);
    // a = samp @ w_out^T + b_out -> fp32 (aliases q_bf/src_bf region)
    mfma_gemm<<<dim3(MTOT / 128, 2), blk, 0, stream>>>(
        samp, wout_b, b_out, nullptr, aout, nullptr, MTOT, DMODEL, DMODEL, 0);
    // x = LN(src + a)  (fp32 + bf16 copy)
    ln_kernel<<<dim3(MTOT / 4), blk, 0, stream>>>(src, aout, g1, be1, x, x_bf);
    // FFN in 2 row-chunks (hidden buffer = MTOT/2 * 1024 bf16)
    for (int c = 0; c < 2; ++c) {
        const size_t ro = (size_t)c * (MTOT / 2);
        mfma_gemm<<<dim3((MTOT / 2) / 128, FFDIM / 128), blk, 0, stream>>>(
            x_bf + ro * 256, w1_b, b1, nullptr, nullptr, h_bf, MTOT / 2, FFDIM, DMODEL, 1);
        mfma_gemm<<<dim3((MTOT / 2) / 128, 2), blk, 0, stream>>>(
            h_bf, w2_b, b2, nullptr, f + ro * 256, nullptr, MTOT / 2, DMODEL, FFDIM, 0);
    }
    // out = LN(x + f)
    ln_kernel<<<dim3(MTOT / 4), blk, 0, stream>>>(x, f, g2, be2, (float*)d_out, nullptr);
}

// Round 3
// 318.895 us; speedup vs baseline: 3.0971x; 1.3903x over previous
//
#include <hip/hip_runtime.h>

// Problem constants
#define B_SZ   4
#define NTOK   5440
#define MTOT   (B_SZ*NTOK)   // 21760
#define DMODEL 256
#define FFDIM  1024

typedef __attribute__((ext_vector_type(8))) __bf16 bf16x8;
typedef __attribute__((ext_vector_type(4))) float  f32x4;

static __device__ __forceinline__ unsigned short f2b(float f) {
    unsigned u = __builtin_bit_cast(unsigned, f);
    u = (u + 0x7FFF + ((u >> 16) & 1)) >> 16;     // RNE (finite inputs)
    return (unsigned short)u;
}
static __device__ __forceinline__ float b2f(unsigned short s) {
    return __builtin_bit_cast(float, (unsigned)s << 16);
}
static __device__ __forceinline__ float lo_bf(unsigned u) {
    return __builtin_bit_cast(float, u << 16);
}
static __device__ __forceinline__ float hi_bf(unsigned u) {
    return __builtin_bit_cast(float, u & 0xffff0000u);
}

// ---------------------------------------------------------------------------
// bf16 MFMA GEMM: C[M,Nout] = A[M,K] @ Wt[Nout,K]^T + bias, opt relu/rowmask.
// 128x128 tile, BK=32, 256 threads (2x2 waves of 64x64), 16x16x32 MFMA.
// bias split: col < bsplit -> bias[col], else bias2[col-bsplit].
// ---------------------------------------------------------------------------
__global__ __launch_bounds__(256)
void mfma_gemm(const unsigned short* __restrict__ A,
               const unsigned short* __restrict__ Wt,
               const float* __restrict__ bias, const float* __restrict__ bias2,
               int bsplit,
               const unsigned char* __restrict__ rowmask,
               float* __restrict__ Cf, unsigned short* __restrict__ Cb,
               int M, int Nout, int K, int relu)
{
    __shared__ unsigned short As[128 * 32];
    __shared__ unsigned short Bs[128 * 32];
    const int tid  = threadIdx.x;
    const int lane = tid & 63;
    const int wave = tid >> 6;
    const int row0 = blockIdx.x * 128, col0 = blockIdx.y * 128;
    const int wr = (wave >> 1) * 64;
    const int wc = (wave & 1) * 64;
    const int mrow = lane & 15, quad = lane >> 4;

    f32x4 acc[4][4] = {};

    const int r0i = (0 * 256 + tid) >> 2, k0i = ((0 * 256 + tid) & 3) * 8;
    const int r1i = (1 * 256 + tid) >> 2, k1i = ((1 * 256 + tid) & 3) * 8;
    const int lds0 = (0 * 256 + wave * 64) * 8;
    const int lds1 = (1 * 256 + wave * 64) * 8;

    for (int k0 = 0; k0 < K; k0 += 32) {
        __syncthreads();
        {
            const unsigned short* ga0 = A  + (size_t)(row0 + r0i) * K + k0 + k0i;
            const unsigned short* gb0 = Wt + (size_t)(col0 + r0i) * K + k0 + k0i;
            const unsigned short* ga1 = A  + (size_t)(row0 + r1i) * K + k0 + k1i;
            const unsigned short* gb1 = Wt + (size_t)(col0 + r1i) * K + k0 + k1i;
            __builtin_amdgcn_global_load_lds((const __attribute__((address_space(1))) void*)ga0,
                                             (__attribute__((address_space(3))) void*)&As[lds0], 16, 0, 0);
            __builtin_amdgcn_global_load_lds((const __attribute__((address_space(1))) void*)gb0,
                                             (__attribute__((address_space(3))) void*)&Bs[lds0], 16, 0, 0);
            __builtin_amdgcn_global_load_lds((const __attribute__((address_space(1))) void*)ga1,
                                             (__attribute__((address_space(3))) void*)&As[lds1], 16, 0, 0);
            __builtin_amdgcn_global_load_lds((const __attribute__((address_space(1))) void*)gb1,
                                             (__attribute__((address_space(3))) void*)&Bs[lds1], 16, 0, 0);
        }
        __syncthreads();

        bf16x8 af[4], bfr[4];
        #pragma unroll
        for (int t4 = 0; t4 < 4; ++t4) {
            af[t4]  = *(const bf16x8*)&As[(wr + t4 * 16 + mrow) * 32 + quad * 8];
            bfr[t4] = *(const bf16x8*)&Bs[(wc + t4 * 16 + mrow) * 32 + quad * 8];
        }
        #pragma unroll
        for (int ti = 0; ti < 4; ++ti)
            #pragma unroll
            for (int tj = 0; tj < 4; ++tj)
                acc[ti][tj] = __builtin_amdgcn_mfma_f32_16x16x32_bf16(
                                  af[ti], bfr[tj], acc[ti][tj], 0, 0, 0);
    }

    // D layout: col=lane&15, row=quad*4+reg  [measured m89/m91]
    #pragma unroll
    for (int tj = 0; tj < 4; ++tj) {
        const int col = col0 + wc + tj * 16 + mrow;
        const float bv = (col < bsplit) ? bias[col] : bias2[col - bsplit];
        #pragma unroll
        for (int ti = 0; ti < 4; ++ti) {
            #pragma unroll
            for (int r = 0; r < 4; ++r) {
                const int row = row0 + wr + ti * 16 + quad * 4 + r;
                float v = acc[ti][tj][r] + bv;
                if (relu) v = fmaxf(v, 0.f);
                if (rowmask && rowmask[row]) v = 0.f;
                if (Cf) Cf[(size_t)row * Nout + col] = v;
                else    Cb[(size_t)row * Nout + col] = f2b(v);
            }
        }
    }
}

// ---------------------------------------------------------------------------
// Deformable sampling. 256 threads per block, 4 tokens per block.
// Phase A: 512 (token,head,point) entries, 2 per thread -> softmax weight +
//   4 packed (byte_off, weight) corners into LDS (int4 = 2 corners).
// Phase B: one wave per token; lane = (head, channel-quad); 64 uint2 gathers.
// oa layout: [MTOT, 384]  (cols 0..255 = offsets, 256..383 = attn logits)
// ---------------------------------------------------------------------------
__global__ __launch_bounds__(256)
void sampling_kernel(const unsigned short* __restrict__ value,
                     const unsigned short* __restrict__ oa,
                     const float* __restrict__ refp,
                     unsigned short* __restrict__ samp)
{
    __shared__ int4 s_pk[1024];      // [(tok*128 + h*16 + p)*2 + j]
    const int t0  = blockIdx.x * 4;
    const int tid = threadIdx.x;

    #pragma unroll
    for (int rep = 0; rep < 2; ++rep) {
        const int e   = rep * 256 + tid;      // 0..511
        const int tok = e >> 7;
        const int hp  = e & 127;
        const int h   = hp >> 4, i16 = hp & 15, l = i16 >> 2;
        const int t   = t0 + tok;

        const float logit = b2f(oa[(size_t)t * 384 + 256 + h * 16 + i16]);
        float mx = logit;
        #pragma unroll
        for (int o = 8; o; o >>= 1) mx = fmaxf(mx, __shfl_xor(mx, o, 16));
        const float ex = __expf(logit - mx);
        float ssum = ex;
        #pragma unroll
        for (int o = 8; o; o >>= 1) ssum += __shfl_xor(ssum, o, 16);
        const float aw = ex / ssum;

        const int   Wl_t[4]   = {64, 32, 16, 8};
        const int   LSTB_t[4] = {0, 4096 * 512, 5120 * 512, 5376 * 512}; // byte row base
        const int   Wl   = Wl_t[l];
        const int   LSTB = LSTB_t[l];
        const float fW   = (float)Wl;

        const unsigned ov = *(const unsigned*)&oa[(size_t)t * 384 + h * 32 + i16 * 2];
        const float ox = lo_bf(ov), oy = hi_bf(ov);
        const float2 rxy = *(const float2*)&refp[(size_t)t * 8 + l * 2];
        const float x = rxy.x * fW + ox - 0.5f;   // normalizer cancels (H==W per level)
        const float y = rxy.y * fW + oy - 0.5f;
        const float x0 = floorf(x), y0 = floorf(y);
        const float fx = x - x0, fy = y - y0;
        const int   ix = (int)x0, iy = (int)y0;
        const bool  vx0 = (ix >= 0) & (ix < Wl), vx1 = (ix + 1 >= 0) & (ix + 1 < Wl);

        #pragma unroll
        for (int j = 0; j < 2; ++j) {              // j = dy
            const int  yv = iy + j;
            const bool vy = (yv >= 0) & (yv < Wl);
            const float wy = (j ? fy : 1.f - fy) * aw;
            const int  rowb = LSTB + yv * Wl * 512;
            const float w0 = (vy & vx0) ? wy * (1.f - fx) : 0.f;
            const float w1 = (vy & vx1) ? wy * fx : 0.f;
            const int  i0 = (vy & vx0) ? rowb + ix * 512 : 0;
            const int  i1 = (vy & vx1) ? rowb + (ix + 1) * 512 : 0;
            s_pk[e * 2 + j] = make_int4(i0, __float_as_int(w0), i1, __float_as_int(w1));
        }
    }
    __syncthreads();

    const int wv_  = tid >> 6;
    const int lane = tid & 63;
    const int h    = lane >> 3, dq = lane & 7;
    const int t    = t0 + wv_;
    const int b    = t / NTOK;
    const char* vb = (const char*)value + ((size_t)b * NTOK * 256 + h * 32 + dq * 4) * 2;
    const int4* pk = s_pk + (wv_ * 128 + h * 16) * 2;

    float a0 = 0.f, a1 = 0.f, a2 = 0.f, a3 = 0.f;
    #pragma unroll 8
    for (int i = 0; i < 32; ++i) {
        const int4 p = pk[i];
        const uint2 u0 = *(const uint2*)(vb + p.x);
        const uint2 u1 = *(const uint2*)(vb + p.z);
        const float w0 = __int_as_float(p.y), w1 = __int_as_float(p.w);
        a0 += lo_bf(u0.x) * w0; a1 += hi_bf(u0.x) * w0;
        a2 += lo_bf(u0.y) * w0; a3 += hi_bf(u0.y) * w0;
        a0 += lo_bf(u1.x) * w1; a1 += hi_bf(u1.x) * w1;
        a2 += lo_bf(u1.y) * w1; a3 += hi_bf(u1.y) * w1;
    }
    ushort4 o;
    o.x = f2b(a0); o.y = f2b(a1); o.z = f2b(a2); o.w = f2b(a3);
    *(ushort4*)(samp + (size_t)t * 256 + h * 32 + dq * 4) = o;
}

// ---------------------------------------------------------------------------
// Fused residual + LayerNorm (D=256), one wave per row; optional bf16 copy.
// ---------------------------------------------------------------------------
__global__ __launch_bounds__(256)
void ln_kernel(const float* __restrict__ resid, const float* __restrict__ y,
               const float* __restrict__ g, const float* __restrict__ be,
               float* __restrict__ out_f, unsigned short* __restrict__ out_b)
{
    const int wave = threadIdx.x >> 6;
    const int lane = threadIdx.x & 63;
    const int row  = blockIdx.x * 4 + wave;
    const size_t base = (size_t)row * 256 + (lane << 2);

    const float4 r = *(const float4*)(resid + base);
    float4 v       = *(const float4*)(y + base);
    v.x += r.x; v.y += r.y; v.z += r.z; v.w += r.w;

    float s  = v.x + v.y + v.z + v.w;
    float ss = v.x * v.x + v.y * v.y + v.z * v.z + v.w * v.w;
    #pragma unroll
    for (int off = 32; off; off >>= 1) {
        s  += __shfl_xor(s, off, 64);
        ss += __shfl_xor(ss, off, 64);
    }
    const float mean = s * (1.f / 256.f);
    const float var  = ss * (1.f / 256.f) - mean * mean;
    const float rstd = rsqrtf(var + 1e-5f);

    const float4 gv = *(const float4*)(g  + (lane << 2));
    const float4 bv = *(const float4*)(be + (lane << 2));
    float4 o;
    o.x = (v.x - mean) * rstd * gv.x + bv.x;
    o.y = (v.y - mean) * rstd * gv.y + bv.y;
    o.z = (v.z - mean) * rstd * gv.z + bv.z;
    o.w = (v.w - mean) * rstd * gv.w + bv.w;
    *(float4*)(out_f + base) = o;
    if (out_b) {
        ushort4 u; u.x = f2b(o.x); u.y = f2b(o.y); u.z = f2b(o.z); u.w = f2b(o.w);
        *(ushort4*)(out_b + base) = u;
    }
}

// ---------------------------------------------------------------------------
// Prep: q_bf = bf16(src+pos), src_bf = bf16(src), plus all 6 weight cvts.
// float4 ranges: [0,1392640) activations; then wv 16384, woff 16384,
// wattn 8192, wout 16384, w1 65536, w2 65536  (total 1581056 = 6176*256).
// ---------------------------------------------------------------------------
__global__ __launch_bounds__(256)
void prep_kernel(const float* __restrict__ src, const float* __restrict__ pos,
                 const float* __restrict__ wv, const float* __restrict__ woff,
                 const float* __restrict__ wattn, const float* __restrict__ wout,
                 const float* __restrict__ w1, const float* __restrict__ w2,
                 unsigned short* __restrict__ q_bf, unsigned short* __restrict__ src_bf,
                 unsigned short* __restrict__ wv_b, unsigned short* __restrict__ woa_b,
                 unsigned short* __restrict__ wout_b,
                 unsigned short* __restrict__ w1_b, unsigned short* __restrict__ w2_b)
{
    const int v = blockIdx.x * 256 + threadIdx.x;
    if (v < 1392640) {
        const float4 s = ((const float4*)src)[v];
        const float4 p = ((const float4*)pos)[v];
        ushort4 qo, so;
        qo.x = f2b(s.x + p.x); qo.y = f2b(s.y + p.y);
        qo.z = f2b(s.z + p.z); qo.w = f2b(s.w + p.w);
        so.x = f2b(s.x); so.y = f2b(s.y); so.z = f2b(s.z); so.w = f2b(s.w);
        ((ushort4*)q_bf)[v]   = qo;
        ((ushort4*)src_bf)[v] = so;
        return;
    }
    const int v2 = v - 1392640;
    const float* s; unsigned short* d; int off;
    if      (v2 <  16384) { s = wv;    d = wv_b;          off = v2; }
    else if (v2 <  32768) { s = woff;  d = woa_b;         off = v2 - 16384; }
    else if (v2 <  40960) { s = wattn; d = woa_b + 65536; off = v2 - 32768; }
    else if (v2 <  57344) { s = wout;  d = wout_b;        off = v2 - 40960; }
    else if (v2 < 122880) { s = w1;    d = w1_b;          off = v2 - 57344; }
    else                  { s = w2;    d = w2_b;          off = v2 - 122880; }
    const float4 f = ((const float4*)s)[off];
    ushort4 u; u.x = f2b(f.x); u.y = f2b(f.y); u.z = f2b(f.z); u.w = f2b(f.w);
    ((ushort4*)d)[off] = u;
}

// ---------------------------------------------------------------------------
extern "C" void kernel_launch(void* const* d_in, const int* in_sizes, int n_in,
                              void* d_out, int out_size, void* d_ws, size_t ws_size,
                              hipStream_t stream) {
    const float* src     = (const float*)d_in[0];
    const float* pos     = (const float*)d_in[1];
    const float* refp    = (const float*)d_in[2];
    const float* w_value = (const float*)d_in[3];
    const float* b_value = (const float*)d_in[4];
    const float* w_off   = (const float*)d_in[5];
    const float* b_off   = (const float*)d_in[6];
    const float* w_attn  = (const float*)d_in[7];
    const float* b_attn  = (const float*)d_in[8];
    const float* w_out   = (const float*)d_in[9];
    const float* b_out   = (const float*)d_in[10];
    const float* g1      = (const float*)d_in[11];
    const float* be1     = (const float*)d_in[12];
    const float* w1      = (const float*)d_in[13];
    const float* b1      = (const float*)d_in[14];
    const float* w2      = (const float*)d_in[15];
    const float* b2      = (const float*)d_in[16];
    const float* g2      = (const float*)d_in[17];
    const float* be2     = (const float*)d_in[18];
    const unsigned char* pmask = (const unsigned char*)d_in[21];

    // ---- workspace (107.3 MB total) ----
    char* ws = (char*)d_ws;
    const size_t SZ16 = (size_t)MTOT * 256 * 2;            // 11,141,120
    unsigned short* q_bf    = (unsigned short*)(ws);
    unsigned short* src_bf  = (unsigned short*)(ws + SZ16);
    float*          aout    = (float*)(ws);                // after q/src dead
    float*          f       = (float*)(ws);                // after aout dead
    unsigned short* value_b = (unsigned short*)(ws + 2 * SZ16);
    unsigned short* oa_b    = (unsigned short*)(ws + 3 * SZ16);        // MTOT*384 bf16
    float*          x       = (float*)(ws + 2 * SZ16);     // after value/oa dead
    unsigned short* samp    = (unsigned short*)(ws + 50135040ULL);
    unsigned short* x_bf    = (unsigned short*)(ws + 50135040ULL);     // after samp dead
    unsigned short* h_bf    = (unsigned short*)(ws + 61276160ULL);     // MTOT*1024 bf16
    unsigned short* wts     = (unsigned short*)(ws + 105840640ULL);
    unsigned short* wv_b    = wts;
    unsigned short* woa_b   = wv_b   + 65536;              // 384*256
    unsigned short* wout_b  = woa_b  + 98304;
    unsigned short* w1_b    = wout_b + 65536;
    unsigned short* w2_b    = w1_b   + 262144;

    const dim3 blk(256);

    prep_kernel<<<dim3(6176), blk, 0, stream>>>(src, pos, w_value, w_off, w_attn,
                                                w_out, w1, w2, q_bf, src_bf,
                                                wv_b, woa_b, wout_b, w1_b, w2_b);
    // value = src @ w_value^T + b_value (+mask) -> bf16
    mfma_gemm<<<dim3(MTOT / 128, 2), blk, 0, stream>>>(
        src_bf, wv_b, b_value, b_value, DMODEL, pmask, nullptr, value_b,
        MTOT, DMODEL, DMODEL, 0);
    // [off | attn] = q @ [w_off; w_attn]^T + [b_off | b_attn] -> bf16 [MTOT,384]
    mfma_gemm<<<dim3(MTOT / 128, 3), blk, 0, stream>>>(
        q_bf, woa_b, b_off, b_attn, DMODEL, nullptr, nullptr, oa_b,
        MTOT, 384, DMODEL, 0);
    // deformable sampling -> bf16
    sampling_kernel<<<dim3(MTOT / 4), blk, 0, stream>>>(value_b, oa_b, refp, samp);
    // a = samp @ w_out^T + b_out -> fp32
    mfma_gemm<<<dim3(MTOT / 128, 2), blk, 0, stream>>>(
        samp, wout_b, b_out, b_out, DMODEL, nullptr, aout, nullptr,
        MTOT, DMODEL, DMODEL, 0);
    // x = LN(src + a)  (fp32 + bf16 copy)
    ln_kernel<<<dim3(MTOT / 4), blk, 0, stream>>>(src, aout, g1, be1, x, x_bf);
    // FFN (single shot)
    mfma_gemm<<<dim3(MTOT / 128, FFDIM / 128), blk, 0, stream>>>(
        x_bf, w1_b, b1, b1, FFDIM, nullptr, nullptr, h_bf, MTOT, FFDIM, DMODEL, 1);
    mfma_gemm<<<dim3(MTOT / 128, 2), blk, 0, stream>>>(
        h_bf, w2_b, b2, b2, DMODEL, nullptr, f, nullptr, MTOT, DMODEL, FFDIM, 0);
    // out = LN(x + f)
    ln_kernel<<<dim3(MTOT / 4), blk, 0, stream>>>(x, f, g2, be2, (float*)d_out, nullptr);
}

// Round 4
// 292.899 us; speedup vs baseline: 3.3719x; 1.0888x over previous
//
#include <hip/hip_runtime.h>

// Problem constants
#define B_SZ   4
#define NTOK   5440
#define MTOT   (B_SZ*NTOK)   // 21760
#define DMODEL 256
#define FFDIM  1024

typedef __attribute__((ext_vector_type(8))) __bf16 bf16x8;
typedef __attribute__((ext_vector_type(4))) float  f32x4;

static __device__ __forceinline__ unsigned short f2b(float f) {
    unsigned u = __builtin_bit_cast(unsigned, f);
    u = (u + 0x7FFF + ((u >> 16) & 1)) >> 16;     // RNE (finite inputs)
    return (unsigned short)u;
}
static __device__ __forceinline__ float b2f(unsigned short s) {
    return __builtin_bit_cast(float, (unsigned)s << 16);
}
static __device__ __forceinline__ float lo_bf(unsigned u) {
    return __builtin_bit_cast(float, u << 16);
}
static __device__ __forceinline__ float hi_bf(unsigned u) {
    return __builtin_bit_cast(float, u & 0xffff0000u);
}

#define GLL(gp, lp) __builtin_amdgcn_global_load_lds( \
    (const __attribute__((address_space(1))) void*)(gp), \
    (__attribute__((address_space(3))) void*)(lp), 16, 0, 0)

// ---------------------------------------------------------------------------
// Fused value + [off|attn] GEMM. K=256, M=MTOT. grid (MTOT/128, 5).
//  y<2 : C=value_b[M,256], A=src_bf, bias=b_value, rowmask applied
//  y>=2: C=oa_b[M,384],    A=q_bf,   bias=b_off|b_attn
// 128x128 tile, BK=32, 256 threads (2x2 waves of 64x64), 16x16x32 MFMA.
// ---------------------------------------------------------------------------
__global__ __launch_bounds__(256)
void qkv_gemm(const unsigned short* __restrict__ src_bf,
              const unsigned short* __restrict__ q_bf,
              const unsigned short* __restrict__ wv_b,
              const unsigned short* __restrict__ woa_b,
              const float* __restrict__ b_value,
              const float* __restrict__ b_off, const float* __restrict__ b_attn,
              const unsigned char* __restrict__ rowmask,
              unsigned short* __restrict__ value_b, unsigned short* __restrict__ oa_b)
{
    const int K = 256;
    const int y = blockIdx.y;
    const bool isv = (y < 2);
    const unsigned short* A  = isv ? src_bf : q_bf;
    const unsigned short* Wt = isv ? wv_b : woa_b;
    unsigned short* C = isv ? value_b : oa_b;
    const int ldc  = isv ? 256 : 384;
    const int col0 = (isv ? y : (y - 2)) * 128;

    __shared__ unsigned short As[128 * 32];
    __shared__ unsigned short Bs[128 * 32];
    const int tid  = threadIdx.x;
    const int lane = tid & 63;
    const int wave = tid >> 6;
    const int row0 = blockIdx.x * 128;
    const int wr = (wave >> 1) * 64, wc = (wave & 1) * 64;
    const int mrow = lane & 15, quad = lane >> 4;

    f32x4 acc[4][4] = {};
    const int ri0 = tid >> 2,            ki0 = (tid & 3) * 8;
    const int ri1 = (256 + tid) >> 2,    ki1 = ((256 + tid) & 3) * 8;
    const int lds0 = (wave * 64) * 8, lds1 = (256 + wave * 64) * 8;

    for (int k0 = 0; k0 < K; k0 += 32) {
        __syncthreads();
        GLL(A  + (size_t)(row0 + ri0) * K + k0 + ki0, &As[lds0]);
        GLL(Wt + (size_t)(col0 + ri0) * K + k0 + ki0, &Bs[lds0]);
        GLL(A  + (size_t)(row0 + ri1) * K + k0 + ki1, &As[lds1]);
        GLL(Wt + (size_t)(col0 + ri1) * K + k0 + ki1, &Bs[lds1]);
        __syncthreads();

        bf16x8 af[4], bfr[4];
        #pragma unroll
        for (int t4 = 0; t4 < 4; ++t4) {
            af[t4]  = *(const bf16x8*)&As[(wr + t4 * 16 + mrow) * 32 + quad * 8];
            bfr[t4] = *(const bf16x8*)&Bs[(wc + t4 * 16 + mrow) * 32 + quad * 8];
        }
        #pragma unroll
        for (int ti = 0; ti < 4; ++ti)
            #pragma unroll
            for (int tj = 0; tj < 4; ++tj)
                acc[ti][tj] = __builtin_amdgcn_mfma_f32_16x16x32_bf16(
                                  af[ti], bfr[tj], acc[ti][tj], 0, 0, 0);
    }

    #pragma unroll
    for (int tj = 0; tj < 4; ++tj) {
        const int col = col0 + wc + tj * 16 + mrow;
        const float bv = isv ? b_value[col] : (col < 256 ? b_off[col] : b_attn[col - 256]);
        #pragma unroll
        for (int ti = 0; ti < 4; ++ti)
            #pragma unroll
            for (int r = 0; r < 4; ++r) {
                const int row = row0 + wr + ti * 16 + quad * 4 + r;
                float v = acc[ti][tj][r] + bv;
                if (isv && rowmask[row]) v = 0.f;
                C[(size_t)row * ldc + col] = f2b(v);
            }
    }
}

// ---------------------------------------------------------------------------
// Generic bf16 MFMA GEMM (FFN1 use): C = A @ Wt^T + bias, relu, bf16 out.
// 128x128 tile, BK=32.
// ---------------------------------------------------------------------------
__global__ __launch_bounds__(256)
void mfma_gemm(const unsigned short* __restrict__ A,
               const unsigned short* __restrict__ Wt,
               const float* __restrict__ bias,
               unsigned short* __restrict__ Cb,
               int M, int Nout, int K, int relu)
{
    __shared__ unsigned short As[128 * 32];
    __shared__ unsigned short Bs[128 * 32];
    const int tid  = threadIdx.x;
    const int lane = tid & 63;
    const int wave = tid >> 6;
    const int row0 = blockIdx.x * 128, col0 = blockIdx.y * 128;
    const int wr = (wave >> 1) * 64, wc = (wave & 1) * 64;
    const int mrow = lane & 15, quad = lane >> 4;

    f32x4 acc[4][4] = {};
    const int ri0 = tid >> 2,            ki0 = (tid & 3) * 8;
    const int ri1 = (256 + tid) >> 2,    ki1 = ((256 + tid) & 3) * 8;
    const int lds0 = (wave * 64) * 8, lds1 = (256 + wave * 64) * 8;

    for (int k0 = 0; k0 < K; k0 += 32) {
        __syncthreads();
        GLL(A  + (size_t)(row0 + ri0) * K + k0 + ki0, &As[lds0]);
        GLL(Wt + (size_t)(col0 + ri0) * K + k0 + ki0, &Bs[lds0]);
        GLL(A  + (size_t)(row0 + ri1) * K + k0 + ki1, &As[lds1]);
        GLL(Wt + (size_t)(col0 + ri1) * K + k0 + ki1, &Bs[lds1]);
        __syncthreads();

        bf16x8 af[4], bfr[4];
        #pragma unroll
        for (int t4 = 0; t4 < 4; ++t4) {
            af[t4]  = *(const bf16x8*)&As[(wr + t4 * 16 + mrow) * 32 + quad * 8];
            bfr[t4] = *(const bf16x8*)&Bs[(wc + t4 * 16 + mrow) * 32 + quad * 8];
        }
        #pragma unroll
        for (int ti = 0; ti < 4; ++ti)
            #pragma unroll
            for (int tj = 0; tj < 4; ++tj)
                acc[ti][tj] = __builtin_amdgcn_mfma_f32_16x16x32_bf16(
                                  af[ti], bfr[tj], acc[ti][tj], 0, 0, 0);
    }

    #pragma unroll
    for (int tj = 0; tj < 4; ++tj) {
        const int col = col0 + wc + tj * 16 + mrow;
        const float bv = bias[col];
        #pragma unroll
        for (int ti = 0; ti < 4; ++ti)
            #pragma unroll
            for (int r = 0; r < 4; ++r) {
                const int row = row0 + wr + ti * 16 + quad * 4 + r;
                float v = acc[ti][tj][r] + bv;
                if (relu) v = fmaxf(v, 0.f);
                Cb[(size_t)row * Nout + col] = f2b(v);
            }
    }
}

// ---------------------------------------------------------------------------
// Fused GEMM (Nout=256) + bias + residual + LayerNorm.
// Tile 64 rows x 256 cols (full D), BK=32, 256 threads = 4 col-waves of 64.
// out_f = LN(resid + A@Wt^T + bias); optional bf16 copy out_b.
// ---------------------------------------------------------------------------
__global__ __launch_bounds__(256)
void gemm_ln(const unsigned short* __restrict__ A,
             const unsigned short* __restrict__ Wt,
             const float* __restrict__ bias,
             const float* __restrict__ resid,
             const float* __restrict__ g, const float* __restrict__ be,
             float* __restrict__ out_f, unsigned short* __restrict__ out_b,
             int K)
{
    __shared__ unsigned short As[64 * 32];    // 4 KB
    __shared__ unsigned short Bs[256 * 32];   // 16 KB
    __shared__ float s_red[64][8];            // [row][wave]=sum, [row][4+wave]=sq

    const int tid  = threadIdx.x;
    const int lane = tid & 63;
    const int wave = tid >> 6;
    const int row0 = blockIdx.x * 64;
    const int mrow = lane & 15, quad = lane >> 4;
    const int colw = wave * 64;

    f32x4 acc[4][4] = {};
    const int ri = tid >> 2, ki = (tid & 3) * 8;

    for (int k0 = 0; k0 < K; k0 += 32) {
        __syncthreads();
        GLL(A + (size_t)(row0 + ri) * K + k0 + ki, &As[(wave * 64) * 8]);
        #pragma unroll
        for (int i = 0; i < 4; ++i)
            GLL(Wt + (size_t)(i * 64 + ri) * K + k0 + ki, &Bs[(i * 256 + wave * 64) * 8]);
        __syncthreads();

        bf16x8 af[4], bfr[4];
        #pragma unroll
        for (int t4 = 0; t4 < 4; ++t4) {
            af[t4]  = *(const bf16x8*)&As[(t4 * 16 + mrow) * 32 + quad * 8];
            bfr[t4] = *(const bf16x8*)&Bs[(colw + t4 * 16 + mrow) * 32 + quad * 8];
        }
        #pragma unroll
        for (int ti = 0; ti < 4; ++ti)
            #pragma unroll
            for (int tj = 0; tj < 4; ++tj)
                acc[ti][tj] = __builtin_amdgcn_mfma_f32_16x16x32_bf16(
                                  af[ti], bfr[tj], acc[ti][tj], 0, 0, 0);
    }

    // per-lane column params
    float bv[4], gv[4], bev[4];
    #pragma unroll
    for (int tj = 0; tj < 4; ++tj) {
        const int col = colw + tj * 16 + mrow;
        bv[tj] = bias[col]; gv[tj] = g[col]; bev[tj] = be[col];
    }

    __syncthreads();   // all fragment ds_reads done before s_red (aliases nothing, but keep order)

    // add bias + residual, accumulate row partials, reduce within quad
    #pragma unroll
    for (int ti = 0; ti < 4; ++ti) {
        #pragma unroll
        for (int r = 0; r < 4; ++r) {
            const int row_local = ti * 16 + quad * 4 + r;
            const int row = row0 + row_local;
            float s = 0.f, sq = 0.f;
            #pragma unroll
            for (int tj = 0; tj < 4; ++tj) {
                const int col = colw + tj * 16 + mrow;
                float t = acc[ti][tj][r] + bv[tj] + resid[(size_t)row * 256 + col];
                acc[ti][tj][r] = t;
                s += t; sq += t * t;
            }
            #pragma unroll
            for (int m = 1; m < 16; m <<= 1) {
                s  += __shfl_xor(s, m, 64);
                sq += __shfl_xor(sq, m, 64);
            }
            if (mrow == 0) { s_red[row_local][wave] = s; s_red[row_local][4 + wave] = sq; }
        }
    }
    __syncthreads();

    #pragma unroll
    for (int ti = 0; ti < 4; ++ti) {
        #pragma unroll
        for (int r = 0; r < 4; ++r) {
            const int row_local = ti * 16 + quad * 4 + r;
            const int row = row0 + row_local;
            const float4 su = *(const float4*)&s_red[row_local][0];
            const float4 qu = *(const float4*)&s_red[row_local][4];
            const float mean = (su.x + su.y + su.z + su.w) * (1.f / 256.f);
            const float var  = (qu.x + qu.y + qu.z + qu.w) * (1.f / 256.f) - mean * mean;
            const float rstd = rsqrtf(var + 1e-5f);
            #pragma unroll
            for (int tj = 0; tj < 4; ++tj) {
                const int col = colw + tj * 16 + mrow;
                const float o = (acc[ti][tj][r] - mean) * rstd * gv[tj] + bev[tj];
                out_f[(size_t)row * 256 + col] = o;
                if (out_b) out_b[(size_t)row * 256 + col] = f2b(o);
            }
        }
    }
}

// ---------------------------------------------------------------------------
// Deformable sampling. 256 threads, 4 tokens per block.
// LDS head stride padded to 33 int4 (528 B) -> heads hit disjoint bank groups.
// ---------------------------------------------------------------------------
__global__ __launch_bounds__(256)
void sampling_kernel(const unsigned short* __restrict__ value,
                     const unsigned short* __restrict__ oa,
                     const float* __restrict__ refp,
                     unsigned short* __restrict__ samp)
{
    __shared__ int4 s_pk[4 * 264];   // [tok*264 + h*33 + p*2 + j]
    const int t0  = blockIdx.x * 4;
    const int tid = threadIdx.x;

    #pragma unroll
    for (int rep = 0; rep < 2; ++rep) {
        const int e   = rep * 256 + tid;      // 0..511
        const int tok = e >> 7;
        const int hp  = e & 127;
        const int h   = hp >> 4, i16 = hp & 15, l = i16 >> 2;
        const int t   = t0 + tok;

        const float logit = b2f(oa[(size_t)t * 384 + 256 + h * 16 + i16]);
        float mx = logit;
        #pragma unroll
        for (int o = 8; o; o >>= 1) mx = fmaxf(mx, __shfl_xor(mx, o, 16));
        const float ex = __expf(logit - mx);
        float ssum = ex;
        #pragma unroll
        for (int o = 8; o; o >>= 1) ssum += __shfl_xor(ssum, o, 16);
        const float aw = ex / ssum;

        const int   Wl_t[4]   = {64, 32, 16, 8};
        const int   LSTB_t[4] = {0, 4096 * 512, 5120 * 512, 5376 * 512};
        const int   Wl   = Wl_t[l];
        const int   LSTB = LSTB_t[l];
        const float fW   = (float)Wl;

        const unsigned ov = *(const unsigned*)&oa[(size_t)t * 384 + h * 32 + i16 * 2];
        const float ox = lo_bf(ov), oy = hi_bf(ov);
        const float2 rxy = *(const float2*)&refp[(size_t)t * 8 + l * 2];
        const float x = rxy.x * fW + ox - 0.5f;
        const float y = rxy.y * fW + oy - 0.5f;
        const float x0 = floorf(x), y0 = floorf(y);
        const float fx = x - x0, fy = y - y0;
        const int   ix = (int)x0, iy = (int)y0;
        const bool  vx0 = (ix >= 0) & (ix < Wl), vx1 = (ix + 1 >= 0) & (ix + 1 < Wl);

        #pragma unroll
        for (int j = 0; j < 2; ++j) {
            const int  yv = iy + j;
            const bool vy = (yv >= 0) & (yv < Wl);
            const float wy = (j ? fy : 1.f - fy) * aw;
            const int  rowb = LSTB + yv * Wl * 512;
            const float w0 = (vy & vx0) ? wy * (1.f - fx) : 0.f;
            const float w1 = (vy & vx1) ? wy * fx : 0.f;
            const int  i0 = (vy & vx0) ? rowb + ix * 512 : 0;
            const int  i1 = (vy & vx1) ? rowb + (ix + 1) * 512 : 0;
            s_pk[tok * 264 + h * 33 + i16 * 2 + j] =
                make_int4(i0, __float_as_int(w0), i1, __float_as_int(w1));
        }
    }
    __syncthreads();

    const int wv_  = tid >> 6;
    const int lane = tid & 63;
    const int h    = lane >> 3, dq = lane & 7;
    const int t    = t0 + wv_;
    const int b    = t / NTOK;
    const char* vb = (const char*)value + ((size_t)b * NTOK * 256 + h * 32 + dq * 4) * 2;
    const int4* pk = s_pk + wv_ * 264 + h * 33;

    float a0 = 0.f, a1 = 0.f, a2 = 0.f, a3 = 0.f;
    #pragma unroll 8
    for (int i = 0; i < 32; ++i) {
        const int4 p = pk[i];
        const uint2 u0 = *(const uint2*)(vb + p.x);
        const uint2 u1 = *(const uint2*)(vb + p.z);
        const float w0 = __int_as_float(p.y), w1 = __int_as_float(p.w);
        a0 += lo_bf(u0.x) * w0; a1 += hi_bf(u0.x) * w0;
        a2 += lo_bf(u0.y) * w0; a3 += hi_bf(u0.y) * w0;
        a0 += lo_bf(u1.x) * w1; a1 += hi_bf(u1.x) * w1;
        a2 += lo_bf(u1.y) * w1; a3 += hi_bf(u1.y) * w1;
    }
    ushort4 o;
    o.x = f2b(a0); o.y = f2b(a1); o.z = f2b(a2); o.w = f2b(a3);
    *(ushort4*)(samp + (size_t)t * 256 + h * 32 + dq * 4) = o;
}

// ---------------------------------------------------------------------------
// Prep: q_bf = bf16(src+pos), src_bf = bf16(src), plus all 6 weight cvts.
// ---------------------------------------------------------------------------
__global__ __launch_bounds__(256)
void prep_kernel(const float* __restrict__ src, const float* __restrict__ pos,
                 const float* __restrict__ wv, const float* __restrict__ woff,
                 const float* __restrict__ wattn, const float* __restrict__ wout,
                 const float* __restrict__ w1, const float* __restrict__ w2,
                 unsigned short* __restrict__ q_bf, unsigned short* __restrict__ src_bf,
                 unsigned short* __restrict__ wv_b, unsigned short* __restrict__ woa_b,
                 unsigned short* __restrict__ wout_b,
                 unsigned short* __restrict__ w1_b, unsigned short* __restrict__ w2_b)
{
    const int v = blockIdx.x * 256 + threadIdx.x;
    if (v < 1392640) {
        const float4 s = ((const float4*)src)[v];
        const float4 p = ((const float4*)pos)[v];
        ushort4 qo, so;
        qo.x = f2b(s.x + p.x); qo.y = f2b(s.y + p.y);
        qo.z = f2b(s.z + p.z); qo.w = f2b(s.w + p.w);
        so.x = f2b(s.x); so.y = f2b(s.y); so.z = f2b(s.z); so.w = f2b(s.w);
        ((ushort4*)q_bf)[v]   = qo;
        ((ushort4*)src_bf)[v] = so;
        return;
    }
    const int v2 = v - 1392640;
    const float* s; unsigned short* d; int off;
    if      (v2 <  16384) { s = wv;    d = wv_b;          off = v2; }
    else if (v2 <  32768) { s = woff;  d = woa_b;         off = v2 - 16384; }
    else if (v2 <  40960) { s = wattn; d = woa_b + 65536; off = v2 - 32768; }
    else if (v2 <  57344) { s = wout;  d = wout_b;        off = v2 - 40960; }
    else if (v2 < 122880) { s = w1;    d = w1_b;          off = v2 - 57344; }
    else                  { s = w2;    d = w2_b;          off = v2 - 122880; }
    const float4 f = ((const float4*)s)[off];
    ushort4 u; u.x = f2b(f.x); u.y = f2b(f.y); u.z = f2b(f.z); u.w = f2b(f.w);
    ((ushort4*)d)[off] = u;
}

// ---------------------------------------------------------------------------
extern "C" void kernel_launch(void* const* d_in, const int* in_sizes, int n_in,
                              void* d_out, int out_size, void* d_ws, size_t ws_size,
                              hipStream_t stream) {
    const float* src     = (const float*)d_in[0];
    const float* pos     = (const float*)d_in[1];
    const float* refp    = (const float*)d_in[2];
    const float* w_value = (const float*)d_in[3];
    const float* b_value = (const float*)d_in[4];
    const float* w_off   = (const float*)d_in[5];
    const float* b_off   = (const float*)d_in[6];
    const float* w_attn  = (const float*)d_in[7];
    const float* b_attn  = (const float*)d_in[8];
    const float* w_out   = (const float*)d_in[9];
    const float* b_out   = (const float*)d_in[10];
    const float* g1      = (const float*)d_in[11];
    const float* be1     = (const float*)d_in[12];
    const float* w1      = (const float*)d_in[13];
    const float* b1      = (const float*)d_in[14];
    const float* w2      = (const float*)d_in[15];
    const float* b2      = (const float*)d_in[16];
    const float* g2      = (const float*)d_in[17];
    const float* be2     = (const float*)d_in[18];
    const unsigned char* pmask = (const unsigned char*)d_in[21];

    // ---- workspace (~107 MB) ----
    char* ws = (char*)d_ws;
    const size_t SZ16 = (size_t)MTOT * 256 * 2;            // 11,141,120 B
    unsigned short* q_bf    = (unsigned short*)(ws);                    // A
    unsigned short* src_bf  = (unsigned short*)(ws + SZ16);             // B
    unsigned short* value_b = (unsigned short*)(ws + 2 * SZ16);         // C
    unsigned short* oa_b    = (unsigned short*)(ws + 3 * SZ16);         // D: MTOT*384
    unsigned short* samp    = (unsigned short*)(ws + 3 * SZ16 + SZ16 * 3 / 2);  // E
    unsigned short* h_bf    = (unsigned short*)(ws + 5 * SZ16 + SZ16 * 3 / 2);  // F: MTOT*1024
    unsigned short* wts     = (unsigned short*)(ws + 9 * SZ16 + SZ16 * 3 / 2);
    // aliases (lifetimes disjoint):
    float*          x       = (float*)(ws);                 // over A+B (dead after qkv)
    unsigned short* x_bf    = (unsigned short*)(ws + 2 * SZ16); // over C (dead after sampling)

    unsigned short* wv_b    = wts;
    unsigned short* woa_b   = wv_b   + 65536;
    unsigned short* wout_b  = woa_b  + 98304;
    unsigned short* w1_b    = wout_b + 65536;
    unsigned short* w2_b    = w1_b   + 262144;

    const dim3 blk(256);

    prep_kernel<<<dim3(6176), blk, 0, stream>>>(src, pos, w_value, w_off, w_attn,
                                                w_out, w1, w2, q_bf, src_bf,
                                                wv_b, woa_b, wout_b, w1_b, w2_b);
    // value / [off|attn]
    qkv_gemm<<<dim3(MTOT / 128, 5), blk, 0, stream>>>(
        src_bf, q_bf, wv_b, woa_b, b_value, b_off, b_attn, pmask, value_b, oa_b);
    // deformable sampling -> bf16
    sampling_kernel<<<dim3(MTOT / 4), blk, 0, stream>>>(value_b, oa_b, refp, samp);
    // x = LN(src + samp @ w_out^T + b_out)  (fp32 + bf16)
    gemm_ln<<<dim3(MTOT / 64), blk, 0, stream>>>(
        samp, wout_b, b_out, src, g1, be1, x, x_bf, DMODEL);
    // h = relu(x @ w1^T + b1)
    mfma_gemm<<<dim3(MTOT / 128, FFDIM / 128), blk, 0, stream>>>(
        x_bf, w1_b, b1, h_bf, MTOT, FFDIM, DMODEL, 1);
    // out = LN(x + h @ w2^T + b2)
    gemm_ln<<<dim3(MTOT / 64), blk, 0, stream>>>(
        h_bf, w2_b, b2, x, g2, be2, (float*)d_out, nullptr, FFDIM);
}

// Round 5
// 271.537 us; speedup vs baseline: 3.6372x; 1.0787x over previous
//
#include <hip/hip_runtime.h>

// Problem constants
#define B_SZ   4
#define NTOK   5440
#define MTOT   (B_SZ*NTOK)   // 21760
#define DMODEL 256
#define FFDIM  1024

typedef __attribute__((ext_vector_type(8))) __bf16 bf16x8;
typedef __attribute__((ext_vector_type(4))) float  f32x4;

static __device__ __forceinline__ unsigned short f2b(float f) {
    unsigned u = __builtin_bit_cast(unsigned, f);
    u = (u + 0x7FFF + ((u >> 16) & 1)) >> 16;     // RNE (finite inputs)
    return (unsigned short)u;
}
static __device__ __forceinline__ float b2f(unsigned short s) {
    return __builtin_bit_cast(float, (unsigned)s << 16);
}
static __device__ __forceinline__ float lo_bf(unsigned u) {
    return __builtin_bit_cast(float, u << 16);
}
static __device__ __forceinline__ float hi_bf(unsigned u) {
    return __builtin_bit_cast(float, u & 0xffff0000u);
}

#define GLL(gp, lp) __builtin_amdgcn_global_load_lds( \
    (const __attribute__((address_space(1))) void*)(gp), \
    (__attribute__((address_space(3))) void*)(lp), 16, 0, 0)

// ---------------------------------------------------------------------------
// Fused value + [off|attn] GEMM. K=256, M=MTOT. grid (5, MTOT/128).
//  blockIdx.x<2 : C=value_b[M,256], A=src_bf, bias=b_value, rowmask applied
//  else         : C=oa_b[M,384],    A=q_bf,   bias=b_off|b_attn
// 128x128 tile, BK=32, 256 threads (2x2 waves of 64x64), 16x16x32 MFMA.
// ---------------------------------------------------------------------------
__global__ __launch_bounds__(256)
void qkv_gemm(const unsigned short* __restrict__ src_bf,
              const unsigned short* __restrict__ q_bf,
              const unsigned short* __restrict__ wv_b,
              const unsigned short* __restrict__ woa_b,
              const float* __restrict__ b_value,
              const float* __restrict__ b_off, const float* __restrict__ b_attn,
              const unsigned char* __restrict__ rowmask,
              unsigned short* __restrict__ value_b, unsigned short* __restrict__ oa_b)
{
    const int K = 256;
    const int y = blockIdx.x;
    const bool isv = (y < 2);
    const unsigned short* A  = isv ? src_bf : q_bf;
    const unsigned short* Wt = isv ? wv_b : woa_b;
    unsigned short* C = isv ? value_b : oa_b;
    const int ldc  = isv ? 256 : 384;
    const int col0 = (isv ? y : (y - 2)) * 128;

    __shared__ unsigned short As[128 * 32];
    __shared__ unsigned short Bs[128 * 32];
    const int tid  = threadIdx.x;
    const int lane = tid & 63;
    const int wave = tid >> 6;
    const int row0 = blockIdx.y * 128;
    const int wr = (wave >> 1) * 64, wc = (wave & 1) * 64;
    const int mrow = lane & 15, quad = lane >> 4;

    f32x4 acc[4][4] = {};
    const int ri0 = tid >> 2,            ki0 = (tid & 3) * 8;
    const int ri1 = (256 + tid) >> 2,    ki1 = ((256 + tid) & 3) * 8;
    const int lds0 = (wave * 64) * 8, lds1 = (256 + wave * 64) * 8;

    for (int k0 = 0; k0 < K; k0 += 32) {
        __syncthreads();
        GLL(A  + (size_t)(row0 + ri0) * K + k0 + ki0, &As[lds0]);
        GLL(Wt + (size_t)(col0 + ri0) * K + k0 + ki0, &Bs[lds0]);
        GLL(A  + (size_t)(row0 + ri1) * K + k0 + ki1, &As[lds1]);
        GLL(Wt + (size_t)(col0 + ri1) * K + k0 + ki1, &Bs[lds1]);
        __syncthreads();

        bf16x8 af[4], bfr[4];
        #pragma unroll
        for (int t4 = 0; t4 < 4; ++t4) {
            af[t4]  = *(const bf16x8*)&As[(wr + t4 * 16 + mrow) * 32 + quad * 8];
            bfr[t4] = *(const bf16x8*)&Bs[(wc + t4 * 16 + mrow) * 32 + quad * 8];
        }
        #pragma unroll
        for (int ti = 0; ti < 4; ++ti)
            #pragma unroll
            for (int tj = 0; tj < 4; ++tj)
                acc[ti][tj] = __builtin_amdgcn_mfma_f32_16x16x32_bf16(
                                  af[ti], bfr[tj], acc[ti][tj], 0, 0, 0);
    }

    #pragma unroll
    for (int tj = 0; tj < 4; ++tj) {
        const int col = col0 + wc + tj * 16 + mrow;
        const float bv = isv ? b_value[col] : (col < 256 ? b_off[col] : b_attn[col - 256]);
        #pragma unroll
        for (int ti = 0; ti < 4; ++ti)
            #pragma unroll
            for (int r = 0; r < 4; ++r) {
                const int row = row0 + wr + ti * 16 + quad * 4 + r;
                float v = acc[ti][tj][r] + bv;
                if (isv && rowmask[row]) v = 0.f;
                C[(size_t)row * ldc + col] = f2b(v);
            }
    }
}

// ---------------------------------------------------------------------------
// Generic bf16 MFMA GEMM (FFN1): C = A @ Wt^T + bias, relu, bf16 out.
// grid (Nout/128, M/128): col index fastest for A-panel L2 reuse.
// ---------------------------------------------------------------------------
__global__ __launch_bounds__(256)
void mfma_gemm(const unsigned short* __restrict__ A,
               const unsigned short* __restrict__ Wt,
               const float* __restrict__ bias,
               unsigned short* __restrict__ Cb,
               int M, int Nout, int K, int relu)
{
    __shared__ unsigned short As[128 * 32];
    __shared__ unsigned short Bs[128 * 32];
    const int tid  = threadIdx.x;
    const int lane = tid & 63;
    const int wave = tid >> 6;
    const int row0 = blockIdx.y * 128, col0 = blockIdx.x * 128;
    const int wr = (wave >> 1) * 64, wc = (wave & 1) * 64;
    const int mrow = lane & 15, quad = lane >> 4;

    f32x4 acc[4][4] = {};
    const int ri0 = tid >> 2,            ki0 = (tid & 3) * 8;
    const int ri1 = (256 + tid) >> 2,    ki1 = ((256 + tid) & 3) * 8;
    const int lds0 = (wave * 64) * 8, lds1 = (256 + wave * 64) * 8;

    for (int k0 = 0; k0 < K; k0 += 32) {
        __syncthreads();
        GLL(A  + (size_t)(row0 + ri0) * K + k0 + ki0, &As[lds0]);
        GLL(Wt + (size_t)(col0 + ri0) * K + k0 + ki0, &Bs[lds0]);
        GLL(A  + (size_t)(row0 + ri1) * K + k0 + ki1, &As[lds1]);
        GLL(Wt + (size_t)(col0 + ri1) * K + k0 + ki1, &Bs[lds1]);
        __syncthreads();

        bf16x8 af[4], bfr[4];
        #pragma unroll
        for (int t4 = 0; t4 < 4; ++t4) {
            af[t4]  = *(const bf16x8*)&As[(wr + t4 * 16 + mrow) * 32 + quad * 8];
            bfr[t4] = *(const bf16x8*)&Bs[(wc + t4 * 16 + mrow) * 32 + quad * 8];
        }
        #pragma unroll
        for (int ti = 0; ti < 4; ++ti)
            #pragma unroll
            for (int tj = 0; tj < 4; ++tj)
                acc[ti][tj] = __builtin_amdgcn_mfma_f32_16x16x32_bf16(
                                  af[ti], bfr[tj], acc[ti][tj], 0, 0, 0);
    }

    #pragma unroll
    for (int tj = 0; tj < 4; ++tj) {
        const int col = col0 + wc + tj * 16 + mrow;
        const float bv = bias[col];
        #pragma unroll
        for (int ti = 0; ti < 4; ++ti)
            #pragma unroll
            for (int r = 0; r < 4; ++r) {
                const int row = row0 + wr + ti * 16 + quad * 4 + r;
                float v = acc[ti][tj][r] + bv;
                if (relu) v = fmaxf(v, 0.f);
                Cb[(size_t)row * Nout + col] = f2b(v);
            }
    }
}

// ---------------------------------------------------------------------------
// Fused GEMM (Nout=256) + bias + residual + LayerNorm.
// Tile 32 rows x 256 cols, BK=32, 256 threads = 4 col-waves of 64.
// grid = M/32 (680 blocks -> ~2.7 blocks/CU, kills the 340-block tail).
// ---------------------------------------------------------------------------
__global__ __launch_bounds__(256)
void gemm_ln(const unsigned short* __restrict__ A,
             const unsigned short* __restrict__ Wt,
             const float* __restrict__ bias,
             const float* __restrict__ resid,
             const float* __restrict__ g, const float* __restrict__ be,
             float* __restrict__ out_f, unsigned short* __restrict__ out_b,
             int K)
{
    __shared__ unsigned short As[32 * 32];    // 2 KB
    __shared__ unsigned short Bs[256 * 32];   // 16 KB
    __shared__ float s_red[32][8];

    const int tid  = threadIdx.x;
    const int lane = tid & 63;
    const int wave = tid >> 6;
    const int row0 = blockIdx.x * 32;
    const int mrow = lane & 15, quad = lane >> 4;
    const int colw = wave * 64;

    f32x4 acc[2][4] = {};
    const int ri = tid >> 2, ki = (tid & 3) * 8;

    for (int k0 = 0; k0 < K; k0 += 32) {
        __syncthreads();
        if (wave < 2)
            GLL(A + (size_t)(row0 + ri) * K + k0 + ki, &As[(wave * 64) * 8]);
        #pragma unroll
        for (int rep = 0; rep < 4; ++rep)
            GLL(Wt + (size_t)(rep * 64 + ri) * K + k0 + ki,
                &Bs[(rep * 256 + wave * 64) * 8]);
        __syncthreads();

        bf16x8 af[2], bfr[4];
        #pragma unroll
        for (int ti = 0; ti < 2; ++ti)
            af[ti] = *(const bf16x8*)&As[(ti * 16 + mrow) * 32 + quad * 8];
        #pragma unroll
        for (int tj = 0; tj < 4; ++tj)
            bfr[tj] = *(const bf16x8*)&Bs[(colw + tj * 16 + mrow) * 32 + quad * 8];
        #pragma unroll
        for (int ti = 0; ti < 2; ++ti)
            #pragma unroll
            for (int tj = 0; tj < 4; ++tj)
                acc[ti][tj] = __builtin_amdgcn_mfma_f32_16x16x32_bf16(
                                  af[ti], bfr[tj], acc[ti][tj], 0, 0, 0);
    }

    float bv[4], gv[4], bev[4];
    #pragma unroll
    for (int tj = 0; tj < 4; ++tj) {
        const int col = colw + tj * 16 + mrow;
        bv[tj] = bias[col]; gv[tj] = g[col]; bev[tj] = be[col];
    }

    #pragma unroll
    for (int ti = 0; ti < 2; ++ti) {
        #pragma unroll
        for (int r = 0; r < 4; ++r) {
            const int row_local = ti * 16 + quad * 4 + r;
            const int row = row0 + row_local;
            float s = 0.f, sq = 0.f;
            #pragma unroll
            for (int tj = 0; tj < 4; ++tj) {
                const int col = colw + tj * 16 + mrow;
                float t = acc[ti][tj][r] + bv[tj] + resid[(size_t)row * 256 + col];
                acc[ti][tj][r] = t;
                s += t; sq += t * t;
            }
            #pragma unroll
            for (int m = 1; m < 16; m <<= 1) {
                s  += __shfl_xor(s, m, 64);
                sq += __shfl_xor(sq, m, 64);
            }
            if (mrow == 0) { s_red[row_local][wave] = s; s_red[row_local][4 + wave] = sq; }
        }
    }
    __syncthreads();

    #pragma unroll
    for (int ti = 0; ti < 2; ++ti) {
        #pragma unroll
        for (int r = 0; r < 4; ++r) {
            const int row_local = ti * 16 + quad * 4 + r;
            const int row = row0 + row_local;
            const float4 su = *(const float4*)&s_red[row_local][0];
            const float4 qu = *(const float4*)&s_red[row_local][4];
            const float mean = (su.x + su.y + su.z + su.w) * (1.f / 256.f);
            const float var  = (qu.x + qu.y + qu.z + qu.w) * (1.f / 256.f) - mean * mean;
            const float rstd = rsqrtf(var + 1e-5f);
            #pragma unroll
            for (int tj = 0; tj < 4; ++tj) {
                const int col = colw + tj * 16 + mrow;
                const float o = (acc[ti][tj][r] - mean) * rstd * gv[tj] + bev[tj];
                out_f[(size_t)row * 256 + col] = o;
                if (out_b) out_b[(size_t)row * 256 + col] = f2b(o);
            }
        }
    }
}

// ---------------------------------------------------------------------------
// Deformable sampling. 256 threads, 8 tokens per block.
// Phase A: 1024 (tok,head,point) entries, 4/thread. Softmax WITHOUT max-sub
//   (logits are O(1)). Corners packed 4 B each: (spatial_idx<<16)|bf16(w).
//   LDS layout: [ (tok*8+h)*68 + point*4 + corner ]  (68 pad -> no conflicts)
// Phase B: wave = 2 tokens; lane=(tok2,h,dq4); per corner one uint4 load
//   (8 channels); depth-2 software pipeline on (pk, gather).
// ---------------------------------------------------------------------------
__global__ __launch_bounds__(256)
void sampling_kernel(const unsigned short* __restrict__ value,
                     const unsigned short* __restrict__ oa,
                     const float* __restrict__ refp,
                     unsigned short* __restrict__ samp)
{
    __shared__ unsigned s_pk[64 * 68];   // 17.4 KB
    const int t0  = blockIdx.x * 8;
    const int tid = threadIdx.x;

    #pragma unroll
    for (int rep = 0; rep < 4; ++rep) {
        const int e   = rep * 256 + tid;      // 0..1023
        const int tok = e >> 7;
        const int hp  = e & 127;
        const int h   = hp >> 4, i16 = hp & 15, l = i16 >> 2;
        const int t   = t0 + tok;

        const float ex = __expf(b2f(oa[(size_t)t * 384 + 256 + h * 16 + i16]));
        float ssum = ex;
        #pragma unroll
        for (int o = 8; o; o >>= 1) ssum += __shfl_xor(ssum, o, 16);
        const float aw = ex / ssum;

        const int   Wl_t[4]  = {64, 32, 16, 8};
        const int   LST_t[4] = {0, 4096, 5120, 5376};
        const int   Wl  = Wl_t[l];
        const int   LST = LST_t[l];
        const float fW  = (float)Wl;

        const unsigned ov = *(const unsigned*)&oa[(size_t)t * 384 + h * 32 + i16 * 2];
        const float ox = lo_bf(ov), oy = hi_bf(ov);
        const float2 rxy = *(const float2*)&refp[(size_t)t * 8 + l * 2];
        const float x = rxy.x * fW + ox - 0.5f;   // normalizer cancels (H==W per level)
        const float y = rxy.y * fW + oy - 0.5f;
        const float x0 = floorf(x), y0 = floorf(y);
        const float fx = x - x0, fy = y - y0;
        const int   ix = (int)x0, iy = (int)y0;
        const bool  vx0 = (ix >= 0) & (ix < Wl), vx1 = (ix + 1 >= 0) & (ix + 1 < Wl);

        const int base = (tok * 8 + h) * 68 + i16 * 4;
        #pragma unroll
        for (int j = 0; j < 2; ++j) {              // j = dy
            const int  yv = iy + j;
            const bool vy = (yv >= 0) & (yv < Wl);
            const float wy = (j ? fy : 1.f - fy) * aw;
            const int  rowi = LST + yv * Wl;
            const float w0 = (vy & vx0) ? wy * (1.f - fx) : 0.f;
            const float w1 = (vy & vx1) ? wy * fx : 0.f;
            const unsigned i0 = (vy & vx0) ? (unsigned)(rowi + ix) : 0u;
            const unsigned i1 = (vy & vx1) ? (unsigned)(rowi + ix + 1) : 0u;
            s_pk[base + j * 2 + 0] = (i0 << 16) | f2b(w0);
            s_pk[base + j * 2 + 1] = (i1 << 16) | f2b(w1);
        }
    }
    __syncthreads();

    const int wv_  = tid >> 6;
    const int lane = tid & 63;
    const int t2   = lane >> 5;
    const int h    = (lane >> 2) & 7;
    const int dq   = lane & 3;                 // 8-channel quad
    const int tok  = wv_ * 2 + t2;
    const int t    = t0 + tok;
    const int b    = t / NTOK;
    const char* vb = (const char*)value + ((size_t)b * NTOK * 256 + h * 32 + dq * 8) * 2;
    const unsigned* sp = s_pk + (tok * 8 + h) * 68;

    float a0 = 0.f, a1 = 0.f, a2 = 0.f, a3 = 0.f;
    float a4 = 0.f, a5 = 0.f, a6 = 0.f, a7 = 0.f;

    unsigned pkc = sp[0];
    uint4 vc = *(const uint4*)(vb + (size_t)(pkc >> 16) * 512);
    #pragma unroll 8
    for (int i = 0; i < 64; ++i) {
        unsigned pkn = 0; uint4 vn = make_uint4(0, 0, 0, 0);
        if (i < 63) {
            pkn = sp[i + 1];
            vn = *(const uint4*)(vb + (size_t)(pkn >> 16) * 512);
        }
        const float w = lo_bf(pkc);
        a0 += lo_bf(vc.x) * w; a1 += hi_bf(vc.x) * w;
        a2 += lo_bf(vc.y) * w; a3 += hi_bf(vc.y) * w;
        a4 += lo_bf(vc.z) * w; a5 += hi_bf(vc.z) * w;
        a6 += lo_bf(vc.w) * w; a7 += hi_bf(vc.w) * w;
        pkc = pkn; vc = vn;
    }
    ushort4 o0, o1;
    o0.x = f2b(a0); o0.y = f2b(a1); o0.z = f2b(a2); o0.w = f2b(a3);
    o1.x = f2b(a4); o1.y = f2b(a5); o1.z = f2b(a6); o1.w = f2b(a7);
    unsigned short* op = samp + (size_t)t * 256 + h * 32 + dq * 8;
    *(ushort4*)(op)     = o0;
    *(ushort4*)(op + 4) = o1;
}

// ---------------------------------------------------------------------------
// Prep: q_bf = bf16(src+pos), src_bf = bf16(src), plus all 6 weight cvts.
// ---------------------------------------------------------------------------
__global__ __launch_bounds__(256)
void prep_kernel(const float* __restrict__ src, const float* __restrict__ pos,
                 const float* __restrict__ wv, const float* __restrict__ woff,
                 const float* __restrict__ wattn, const float* __restrict__ wout,
                 const float* __restrict__ w1, const float* __restrict__ w2,
                 unsigned short* __restrict__ q_bf, unsigned short* __restrict__ src_bf,
                 unsigned short* __restrict__ wv_b, unsigned short* __restrict__ woa_b,
                 unsigned short* __restrict__ wout_b,
                 unsigned short* __restrict__ w1_b, unsigned short* __restrict__ w2_b)
{
    const int v = blockIdx.x * 256 + threadIdx.x;
    if (v < 1392640) {
        const float4 s = ((const float4*)src)[v];
        const float4 p = ((const float4*)pos)[v];
        ushort4 qo, so;
        qo.x = f2b(s.x + p.x); qo.y = f2b(s.y + p.y);
        qo.z = f2b(s.z + p.z); qo.w = f2b(s.w + p.w);
        so.x = f2b(s.x); so.y = f2b(s.y); so.z = f2b(s.z); so.w = f2b(s.w);
        ((ushort4*)q_bf)[v]   = qo;
        ((ushort4*)src_bf)[v] = so;
        return;
    }
    const int v2 = v - 1392640;
    const float* s; unsigned short* d; int off;
    if      (v2 <  16384) { s = wv;    d = wv_b;          off = v2; }
    else if (v2 <  32768) { s = woff;  d = woa_b;         off = v2 - 16384; }
    else if (v2 <  40960) { s = wattn; d = woa_b + 65536; off = v2 - 32768; }
    else if (v2 <  57344) { s = wout;  d = wout_b;        off = v2 - 40960; }
    else if (v2 < 122880) { s = w1;    d = w1_b;          off = v2 - 57344; }
    else                  { s = w2;    d = w2_b;          off = v2 - 122880; }
    const float4 f = ((const float4*)s)[off];
    ushort4 u; u.x = f2b(f.x); u.y = f2b(f.y); u.z = f2b(f.z); u.w = f2b(f.w);
    ((ushort4*)d)[off] = u;
}

// ---------------------------------------------------------------------------
extern "C" void kernel_launch(void* const* d_in, const int* in_sizes, int n_in,
                              void* d_out, int out_size, void* d_ws, size_t ws_size,
                              hipStream_t stream) {
    const float* src     = (const float*)d_in[0];
    const float* pos     = (const float*)d_in[1];
    const float* refp    = (const float*)d_in[2];
    const float* w_value = (const float*)d_in[3];
    const float* b_value = (const float*)d_in[4];
    const float* w_off   = (const float*)d_in[5];
    const float* b_off   = (const float*)d_in[6];
    const float* w_attn  = (const float*)d_in[7];
    const float* b_attn  = (const float*)d_in[8];
    const float* w_out   = (const float*)d_in[9];
    const float* b_out   = (const float*)d_in[10];
    const float* g1      = (const float*)d_in[11];
    const float* be1     = (const float*)d_in[12];
    const float* w1      = (const float*)d_in[13];
    const float* b1      = (const float*)d_in[14];
    const float* w2      = (const float*)d_in[15];
    const float* b2      = (const float*)d_in[16];
    const float* g2      = (const float*)d_in[17];
    const float* be2     = (const float*)d_in[18];
    const unsigned char* pmask = (const unsigned char*)d_in[21];

    // ---- workspace (~107 MB) ----
    char* ws = (char*)d_ws;
    const size_t SZ16 = (size_t)MTOT * 256 * 2;            // 11,141,120 B
    unsigned short* q_bf    = (unsigned short*)(ws);
    unsigned short* src_bf  = (unsigned short*)(ws + SZ16);
    unsigned short* value_b = (unsigned short*)(ws + 2 * SZ16);
    unsigned short* oa_b    = (unsigned short*)(ws + 3 * SZ16);         // MTOT*384
    unsigned short* samp    = (unsigned short*)(ws + 3 * SZ16 + SZ16 * 3 / 2);
    unsigned short* h_bf    = (unsigned short*)(ws + 5 * SZ16 + SZ16 * 3 / 2);  // MTOT*1024
    unsigned short* wts     = (unsigned short*)(ws + 9 * SZ16 + SZ16 * 3 / 2);
    // aliases (lifetimes disjoint):
    float*          x       = (float*)(ws);                     // over q/src_bf
    unsigned short* x_bf    = (unsigned short*)(ws + 2 * SZ16); // over value_b

    unsigned short* wv_b    = wts;
    unsigned short* woa_b   = wv_b   + 65536;
    unsigned short* wout_b  = woa_b  + 98304;
    unsigned short* w1_b    = wout_b + 65536;
    unsigned short* w2_b    = w1_b   + 262144;

    const dim3 blk(256);

    prep_kernel<<<dim3(6176), blk, 0, stream>>>(src, pos, w_value, w_off, w_attn,
                                                w_out, w1, w2, q_bf, src_bf,
                                                wv_b, woa_b, wout_b, w1_b, w2_b);
    // value / [off|attn]  (col index fastest)
    qkv_gemm<<<dim3(5, MTOT / 128), blk, 0, stream>>>(
        src_bf, q_bf, wv_b, woa_b, b_value, b_off, b_attn, pmask, value_b, oa_b);
    // deformable sampling -> bf16
    sampling_kernel<<<dim3(MTOT / 8), blk, 0, stream>>>(value_b, oa_b, refp, samp);
    // x = LN(src + samp @ w_out^T + b_out)  (fp32 + bf16)
    gemm_ln<<<dim3(MTOT / 32), blk, 0, stream>>>(
        samp, wout_b, b_out, src, g1, be1, x, x_bf, DMODEL);
    // h = relu(x @ w1^T + b1)  (col index fastest)
    mfma_gemm<<<dim3(FFDIM / 128, MTOT / 128), blk, 0, stream>>>(
        x_bf, w1_b, b1, h_bf, MTOT, FFDIM, DMODEL, 1);
    // out = LN(x + h @ w2^T + b2)
    gemm_ln<<<dim3(MTOT / 32), blk, 0, stream>>>(
        h_bf, w2_b, b2, x, g2, be2, (float*)d_out, nullptr, FFDIM);
}